// Round 10
// baseline (380.073 us; speedup 1.0000x reference)
//
#include <hip/hip_runtime.h>
#include <hip/hip_bf16.h>

// ---------------- problem constants ----------------
#define HE   12
#define HD   64
#define Cc   768
#define C2   1536
#define C4   3072
#define N7   5376
#define Bb   2
#define Ss   2048      // H*W*D = 16*16*8
#define BSr  4096      // B*S rows
#define PI_F 3.14159265358979f

using f32x4  = __attribute__((ext_vector_type(4))) float;
using short8 = __attribute__((ext_vector_type(8))) short;

__device__ __forceinline__ unsigned short f2b(float f) {
    union { float f; unsigned int u; } v; v.f = f;
    unsigned int u = v.u;
    unsigned int r = (u + 0x7fffu + ((u >> 16) & 1u)) >> 16;
    return (unsigned short)r;
}
__device__ __forceinline__ unsigned short f2bt(float f) {   // truncating
    union { float f; unsigned int u; } v; v.f = f;
    return (unsigned short)(v.u >> 16);
}
__device__ __forceinline__ float b2f(unsigned short s) {
    union { unsigned int u; float f; } v; v.u = ((unsigned int)s) << 16;
    return v.f;
}
__device__ __forceinline__ f32x4 mfma16(short8 a, short8 b, f32x4 c) {
    return __builtin_amdgcn_mfma_f32_16x16x32_bf16(a, b, c, 0, 0, 0);
}
// async global->LDS, 16 B per lane. LDS dest resolves to wave-uniform base + lane*16.
__device__ __forceinline__ void gl_lds16(const unsigned short* g, unsigned short* l) {
    __builtin_amdgcn_global_load_lds(
        (const __attribute__((address_space(1))) unsigned int*)(const void*)g,
        (__attribute__((address_space(3))) unsigned int*)(void*)l, 16, 0, 0);
}
// bijective XCD swizzle (requires nwg % 8 == 0)
__device__ __forceinline__ void xcd_tile(int& bx, int& by) {
    int nx = gridDim.x;
    int flat = blockIdx.y * nx + blockIdx.x;
    int nwg = nx * gridDim.y;
    int swz = (flat & 7) * (nwg >> 3) + (flat >> 3);
    bx = swz % nx; by = swz / nx;
}

union U8 { uint4 v; unsigned short u[8]; };

// ---------------- 1. tiled transpose f32 -> bf16 (weights) ----------------
__global__ __launch_bounds__(256) void transpose_w(const float* __restrict__ src,
                                                   unsigned short* __restrict__ dst,
                                                   int R, int Ccol) {
    __shared__ float tile[32][33];
    int tx = threadIdx.x & 31, ty = threadIdx.x >> 5;
    int rt = blockIdx.y * 32, ct = blockIdx.x * 32;
#pragma unroll
    for (int i = 0; i < 4; ++i)
        tile[ty + i * 8][tx] = src[(size_t)(rt + ty + i * 8) * Ccol + ct + tx];
    __syncthreads();
#pragma unroll
    for (int i = 0; i < 4; ++i)
        dst[(size_t)(ct + ty + i * 8) * R + rt + tx] = f2b(tile[tx][ty + i * 8]);
}

// ---------------- 2. groupnorm stats ----------------
__global__ __launch_bounds__(256) void gn_stats(const float* __restrict__ x,
                                                float* __restrict__ stat) {
    int j = blockIdx.x;
    const float4* p = (const float4*)(x + (size_t)j * 131072);
    float s = 0.f, ss = 0.f;
    for (int i = threadIdx.x; i < 32768; i += 256) {
        float4 v = p[i];
        s  += v.x + v.y + v.z + v.w;
        ss += v.x * v.x + v.y * v.y + v.z * v.z + v.w * v.w;
    }
#pragma unroll
    for (int m = 1; m < 64; m <<= 1) { s += __shfl_xor(s, m); ss += __shfl_xor(ss, m); }
    __shared__ float ls[4], lss[4];
    int wid = threadIdx.x >> 6;
    if ((threadIdx.x & 63) == 0) { ls[wid] = s; lss[wid] = ss; }
    __syncthreads();
    if (threadIdx.x == 0) {
        s = ls[0] + ls[1] + ls[2] + ls[3];
        ss = lss[0] + lss[1] + lss[2] + lss[3];
        float mu  = s / 131072.0f;
        float var = ss / 131072.0f - mu * mu;
        stat[j * 2]     = mu;
        stat[j * 2 + 1] = rsqrtf(var + 1e-5f);
    }
}

// ---------------- 3. normalize + transpose (B,C,S) -> t bf16 (B*S, C) ----------
__global__ __launch_bounds__(256) void norm_transpose(const float* __restrict__ x,
                                                      const float* __restrict__ stat,
                                                      const float* __restrict__ w,
                                                      const float* __restrict__ bgn,
                                                      unsigned short* __restrict__ t) {
    __shared__ float tile[32][33];
    int b = blockIdx.z;
    int st = blockIdx.x * 32, ct = blockIdx.y * 32;
    int tx = threadIdx.x & 31, ty = threadIdx.x >> 5;
#pragma unroll
    for (int i = 0; i < 4; ++i) {
        int c = ct + ty + i * 8;
        int g = c >> 6;
        float mu = stat[(b * 12 + g) * 2], rs = stat[(b * 12 + g) * 2 + 1];
        float v = x[(size_t)(b * Cc + c) * Ss + st + tx];
        tile[ty + i * 8][tx] = (v - mu) * rs * w[c] + bgn[c];
    }
    __syncthreads();
#pragma unroll
    for (int i = 0; i < 4; ++i) {
        int s = st + ty + i * 8, c = ct + tx;
        t[(size_t)(b * Ss + s) * Cc + c] = f2b(tile[tx][ty + i * 8]);
    }
}

// ---------------- 4. 128x128x32 bf16 GEMM: 2-phase dbuf + deswizzled LDS --------
// LDS element (row, kcblk) stored at linear block kcblk ^ ((row>>1)&3): frag reads
// spread banks. gl_lds dest stays linear; global SOURCE is pre-swizzled (rule #21).
template<bool ACCUM, bool BIAS, bool OUTBF16>
__global__ __launch_bounds__(256) void gemm128(const unsigned short* __restrict__ A,
                                               const unsigned short* __restrict__ Bt,
                                               const float* __restrict__ bias,
                                               void* __restrict__ Cout,
                                               int M, int N, int K) {
    __shared__ __align__(16) unsigned short As[2][128 * 32];
    __shared__ __align__(16) unsigned short Bs[2][128 * 32];
    const int tid = threadIdx.x;
    const int wid = tid >> 6, lane = tid & 63;
    const int lr = lane & 15, lh = lane >> 4;
    const int wr = wid >> 1, wc = wid & 1;
    int bx, by; xcd_tile(bx, by);
    const int row0 = by * 128, col0 = bx * 128;
    // pre-swizzled source: dest block (tid&3) holds source block (tid&3)^((row>>1)&3)
    const int srow = tid >> 2;
    const int kcs  = (((tid & 3) ^ ((tid >> 3) & 3)) * 8);
    const unsigned short* ga = A  + (size_t)(row0 + srow) * K + kcs;
    const unsigned short* gb = Bt + (size_t)(col0 + srow) * K + kcs;
    const int csw = ((lr >> 1) & 3) << 3;      // read-side XOR (elems)
    f32x4 acc[4][4] = {};

    auto STAGE = [&](int buf, int k0) {
        gl_lds16(ga + k0,          &As[buf][tid * 8]);
        gl_lds16(ga + 64 * K + k0, &As[buf][2048 + tid * 8]);
        gl_lds16(gb + k0,          &Bs[buf][tid * 8]);
        gl_lds16(gb + 64 * K + k0, &Bs[buf][2048 + tid * 8]);
    };

    STAGE(0, 0);
    __syncthreads();
    for (int k0 = 0; k0 < K; k0 += 32) {
        const int cur = (k0 >> 5) & 1;
        if (k0 + 32 < K) STAGE(cur ^ 1, k0 + 32);   // loads fly under the MFMAs
        short8 af[4], bfr[4];
#pragma unroll
        for (int m = 0; m < 4; ++m)
            af[m]  = *(const short8*)&As[cur][(wr * 64 + m * 16 + lr) * 32 + ((lh << 3) ^ csw)];
#pragma unroll
        for (int n = 0; n < 4; ++n)
            bfr[n] = *(const short8*)&Bs[cur][(wc * 64 + n * 16 + lr) * 32 + ((lh << 3) ^ csw)];
#pragma unroll
        for (int m = 0; m < 4; ++m)
#pragma unroll
            for (int n = 0; n < 4; ++n)
                acc[m][n] = mfma16(af[m], bfr[n], acc[m][n]);
        __syncthreads();   // drains vmcnt(0): next buffer staged; reads of cur done
    }

#pragma unroll
    for (int m = 0; m < 4; ++m)
#pragma unroll
        for (int n = 0; n < 4; ++n) {
            int row = row0 + wr * 64 + m * 16 + lh * 4;
            int col = col0 + wc * 64 + n * 16 + lr;
            float bv = BIAS ? bias[col] : 0.0f;
#pragma unroll
            for (int r = 0; r < 4; ++r) {
                size_t idx = (size_t)(row + r) * N + col;
                float v = acc[m][n][r] + bv;
                if (ACCUM) v += ((const float*)Cout)[idx];
                if (OUTBF16) ((unsigned short*)Cout)[idx] = f2b(v);
                else         ((float*)Cout)[idx] = v;
            }
        }
}

// ---- 4b. final GEMM: oacc-accumulate + gamma/residual/transpose epilogue ------
__global__ __launch_bounds__(256) void gemm_fin(const unsigned short* __restrict__ A,
                                                const unsigned short* __restrict__ Bt,
                                                const float* __restrict__ bo,
                                                const float* __restrict__ oaccIn,
                                                const float* __restrict__ x,
                                                const float* __restrict__ gamma,
                                                float* __restrict__ out,
                                                int M, int N, int K) {
    __shared__ __align__(16) unsigned short As[2][128 * 32];
    __shared__ __align__(16) unsigned short Bs[2][128 * 32];
    const int tid = threadIdx.x;
    const int wid = tid >> 6, lane = tid & 63;
    const int lr = lane & 15, lh = lane >> 4;
    const int wr = wid >> 1, wc = wid & 1;
    int bx, by; xcd_tile(bx, by);
    const int row0 = by * 128, col0 = bx * 128;
    const int srow = tid >> 2;
    const int kcs  = (((tid & 3) ^ ((tid >> 3) & 3)) * 8);
    const unsigned short* ga = A  + (size_t)(row0 + srow) * K + kcs;
    const unsigned short* gb = Bt + (size_t)(col0 + srow) * K + kcs;
    const int csw = ((lr >> 1) & 3) << 3;
    f32x4 acc[4][4] = {};

    auto STAGE = [&](int buf, int k0) {
        gl_lds16(ga + k0,          &As[buf][tid * 8]);
        gl_lds16(ga + 64 * K + k0, &As[buf][2048 + tid * 8]);
        gl_lds16(gb + k0,          &Bs[buf][tid * 8]);
        gl_lds16(gb + 64 * K + k0, &Bs[buf][2048 + tid * 8]);
    };

    STAGE(0, 0);
    __syncthreads();
    for (int k0 = 0; k0 < K; k0 += 32) {
        const int cur = (k0 >> 5) & 1;
        if (k0 + 32 < K) STAGE(cur ^ 1, k0 + 32);
        short8 af[4], bfr[4];
#pragma unroll
        for (int m = 0; m < 4; ++m)
            af[m]  = *(const short8*)&As[cur][(wr * 64 + m * 16 + lr) * 32 + ((lh << 3) ^ csw)];
#pragma unroll
        for (int n = 0; n < 4; ++n)
            bfr[n] = *(const short8*)&Bs[cur][(wc * 64 + n * 16 + lr) * 32 + ((lh << 3) ^ csw)];
#pragma unroll
        for (int m = 0; m < 4; ++m)
#pragma unroll
            for (int n = 0; n < 4; ++n)
                acc[m][n] = mfma16(af[m], bfr[n], acc[m][n]);
        __syncthreads();
    }

#pragma unroll
    for (int m = 0; m < 4; ++m)
#pragma unroll
        for (int n = 0; n < 4; ++n) {
            int row = row0 + wr * 64 + m * 16 + lh * 4;
            int col = col0 + wc * 64 + n * 16 + lr;
            float bv = bo[col], gv = gamma[col];
#pragma unroll
            for (int r = 0; r < 4; ++r) {
                int rw = row + r;
                float v = acc[m][n][r] + bv + oaccIn[(size_t)rw * N + col];
                int b = rw >> 11, s = rw & 2047;
                size_t oidx = (size_t)(b * Cc + col) * Ss + s;
                out[oidx] = gv * v + x[oidx];
            }
        }
}

// ---------------- 5. per-(b,s,head) LN + RoPE on q,k ; copy v ----------------
__global__ __launch_bounds__(256) void qkv_prep(const unsigned short* __restrict__ fused,
                                                const float* __restrict__ qnw, const float* __restrict__ qnb,
                                                const float* __restrict__ knw, const float* __restrict__ knb,
                                                unsigned short* __restrict__ qf,
                                                unsigned short* __restrict__ kf,
                                                unsigned short* __restrict__ vf) {
    const int wid = threadIdx.x >> 6, lane = threadIdx.x & 63;
    const int job = blockIdx.x * 4 + wid;
    const int srow = job / 12, h = job % 12;
    const int b = srow >> 11, s = srow & 2047;

    size_t base = (size_t)srow * N7 + C4 + h * HD;
    float qv = b2f(fused[base + lane]);
    float kv = b2f(fused[base + Cc + lane]);
    float vv = b2f(fused[base + 2 * Cc + lane]);

    float qs = qv, ks = kv;
#pragma unroll
    for (int m = 1; m < 64; m <<= 1) { qs += __shfl_xor(qs, m); ks += __shfl_xor(ks, m); }
    float qmu = qs * (1.0f / 64.0f), kmu = ks * (1.0f / 64.0f);
    float qd = qv - qmu, kd = kv - kmu;
    float qv2 = qd * qd, kv2 = kd * kd;
#pragma unroll
    for (int m = 1; m < 64; m <<= 1) { qv2 += __shfl_xor(qv2, m); kv2 += __shfl_xor(kv2, m); }
    float qn = qd * rsqrtf(qv2 * (1.0f / 64.0f) + 1e-5f) * qnw[lane] + qnb[lane];
    float kn = kd * rsqrtf(kv2 * (1.0f / 64.0f) + 1e-5f) * knw[lane] + knb[lane];

    if (lane < 48) {
        int axis = lane >> 4, ii = (lane & 15) >> 1;
        float basef = (1.0f + (float)ii * (127.0f / 7.0f)) * PI_F;
        int   pos_i = (axis == 0) ? (s >> 7) : (axis == 1) ? ((s >> 3) & 15) : (s & 7);
        float denom = (axis == 2) ? 7.0f : 15.0f;
        float pos   = -1.0f + 2.0f * (float)pos_i / denom;
        float ang   = pos * basef;
        float sn, cs;
        sincosf(ang, &sn, &cs);
        float qp = __shfl_xor(qn, 1);
        float kp = __shfl_xor(kn, 1);
        qn = (lane & 1) ? (qn * cs + qp * sn) : (qn * cs - qp * sn);
        kn = (lane & 1) ? (kn * cs + kp * sn) : (kn * cs - kp * sn);
    }

    size_t obase = ((size_t)(b * 12 + h) * Ss + s) * HD + lane;
    qf[obase] = f2b(qn);
    kf[obase] = f2b(kn);
    vf[obase] = f2b(vv);
}

// ---------------- 6. ffa = silu(gate) * xh ----------------
__global__ __launch_bounds__(256) void ffa_prep(const unsigned short* __restrict__ fused,
                                                unsigned short* __restrict__ ffa) {
    int i8 = blockIdx.x * 256 + threadIdx.x;
    int row = i8 / 192, co = (i8 % 192) * 8;
    U8 xa, ga, oa;
    xa.v = *(const uint4*)&fused[(size_t)row * N7 + co];
    ga.v = *(const uint4*)&fused[(size_t)row * N7 + C2 + co];
#pragma unroll
    for (int j = 0; j < 8; ++j) {
        float g = b2f(ga.u[j]);
        float xh = b2f(xa.u[j]);
        float sg = 1.0f / (1.0f + __expf(-g));
        oa.u[j] = f2b(g * sg * xh);
    }
    *(uint4*)&ffa[(size_t)row * C2 + co] = oa.v;
}

// ---------------- 7. flash attention, split-KV x2, fixed-max softmax ------------
// With fixed max, o and l are pure sums over keys -> KV halves combine by addition.
// Stride-72 rows (144B = 4 dwords mod 32 banks): b128 frag reads are 2-way = free.
__global__ __launch_bounds__(256) void attn64(const unsigned short* __restrict__ qf,
                                              const unsigned short* __restrict__ kf,
                                              const unsigned short* __restrict__ vf,
                                              float* __restrict__ opart) {
    __shared__ __align__(16) unsigned short Ks[64][72];
    __shared__ __align__(16) unsigned short Vt[64][72];    // Vt[d][key], swizzled
    __shared__ __align__(16) unsigned short Ps[4][16][72]; // wave-private
    const int tid = threadIdx.x, wid = tid >> 6, lane = tid & 63;
    const int lr = lane & 15, lh = lane >> 4;
    const int bh = blockIdx.y, qt = blockIdx.x, half = blockIdx.z;
    const size_t kvbase = (size_t)bh * Ss * HD;

    const int qrow = qt * 64 + wid * 16 + lr;
    short8 qa0 = *(const short8*)&qf[kvbase + (size_t)qrow * HD + lh * 8];
    short8 qa1 = *(const short8*)&qf[kvbase + (size_t)qrow * HD + 32 + lh * 8];

    // staging geometry: this thread owns rows r0, r0+32 of each tile, d-cols kc0..+7
    const int r0 = tid >> 3, kc0 = (tid & 7) * 8;
    const int sv0 = (((r0 >> 3) ^ (kc0 >> 3)) << 3) | (r0 & 7);
    const int sv1 = ((((r0 >> 3) + 4) ^ (kc0 >> 3)) << 3) | (r0 & 7);
    const unsigned short* kptr = kf + kvbase + (size_t)(half * 16 * 64 + r0) * HD + kc0;
    const unsigned short* vptr = vf + kvbase + (size_t)(half * 16 * 64 + r0) * HD + kc0;

    const short8 ones = {0x3F80, 0x3F80, 0x3F80, 0x3F80, 0x3F80, 0x3F80, 0x3F80, 0x3F80};
    const float c1 = 0.125f * 1.44269504f;     // scale * log2(e)
    const float c2 = 23.08312065f;             // 16 * log2(e)
    const int rxb = (lr >> 2) & 3;             // Ps read swizzle (row = lr)

    f32x4 oacc[4] = {};
    f32x4 lacc = {};

    // prologue: tile 0 of this half into regs
    uint4 kreg0 = *(const uint4*)kptr;
    uint4 kreg1 = *(const uint4*)(kptr + 32 * HD);
    U8 vreg0, vreg1;
    vreg0.v = *(const uint4*)vptr;
    vreg1.v = *(const uint4*)(vptr + 32 * HD);

    for (int kt = 0; kt < 16; ++kt) {
        *(uint4*)&Ks[r0][kc0]      = kreg0;
        *(uint4*)&Ks[r0 + 32][kc0] = kreg1;
#pragma unroll
        for (int j = 0; j < 8; ++j) Vt[kc0 + j][sv0] = vreg0.u[j];
#pragma unroll
        for (int j = 0; j < 8; ++j) Vt[kc0 + j][sv1] = vreg1.u[j];
        __syncthreads();

        if (kt < 15) {      // issue next-tile loads; latency hides under compute
            const unsigned short* kp = kptr + (size_t)(kt + 1) * 64 * HD;
            const unsigned short* vp = vptr + (size_t)(kt + 1) * 64 * HD;
            kreg0   = *(const uint4*)kp;
            kreg1   = *(const uint4*)(kp + 32 * HD);
            vreg0.v = *(const uint4*)vp;
            vreg1.v = *(const uint4*)(vp + 32 * HD);
        }

        f32x4 sc[4];
#pragma unroll
        for (int n = 0; n < 4; ++n) {
            f32x4 z = {0.f, 0.f, 0.f, 0.f};
            short8 k0 = *(const short8*)&Ks[n * 16 + lr][lh * 8];
            short8 k1 = *(const short8*)&Ks[n * 16 + lr][32 + lh * 8];
            z = mfma16(qa0, k0, z);
            z = mfma16(qa1, k1, z);
            sc[n] = z;
        }

#pragma unroll
        for (int n = 0; n < 4; ++n)
#pragma unroll
            for (int r = 0; r < 4; ++r)
                sc[n][r] = exp2f(sc[n][r] * c1 - c2);

#pragma unroll
        for (int r = 0; r < 4; ++r) {
            int prow = lh * 4 + r;
            int lo = lr & 7, lr3 = lr >> 3;
            Ps[wid][prow][(((0 + lr3) ^ lh) << 3) | lo] = f2bt(sc[0][r]);
            Ps[wid][prow][(((2 + lr3) ^ lh) << 3) | lo] = f2bt(sc[1][r]);
            Ps[wid][prow][(((4 + lr3) ^ lh) << 3) | lo] = f2bt(sc[2][r]);
            Ps[wid][prow][(((6 + lr3) ^ lh) << 3) | lo] = f2bt(sc[3][r]);
        }

        short8 pa0 = *(const short8*)&Ps[wid][lr][((lh ^ rxb) & 7) * 8];
        short8 pa1 = *(const short8*)&Ps[wid][lr][(((lh + 4) ^ rxb) & 7) * 8];
        lacc = mfma16(pa0, ones, lacc);
        lacc = mfma16(pa1, ones, lacc);
#pragma unroll
        for (int n = 0; n < 4; ++n) {
            int dv = (2 * n + (lr >> 3)) & 7;
            short8 v0 = *(const short8*)&Vt[n * 16 + lr][((lh ^ dv) & 7) * 8];
            short8 v1 = *(const short8*)&Vt[n * 16 + lr][(((lh + 4) ^ dv) & 7) * 8];
            oacc[n] = mfma16(pa0, v0, oacc[n]);
            oacc[n] = mfma16(pa1, v1, oacc[n]);
        }
        __syncthreads();
    }

    // store f32 partials: chunk = ((bh*32+qt)*2+half), layout [64q][64d] + l[64q]
    const size_t cb = ((size_t)((bh * 32 + qt) * 2 + half)) * 4160;
#pragma unroll
    for (int n = 0; n < 4; ++n)
#pragma unroll
        for (int r = 0; r < 4; ++r)
            opart[cb + (size_t)(wid * 16 + lh * 4 + r) * 64 + n * 16 + lr] = oacc[n][r];
    if (lr == 0)
#pragma unroll
        for (int r = 0; r < 4; ++r)
            opart[cb + 4096 + wid * 16 + lh * 4 + r] = lacc[r];
}

// ---------------- 7b. combine split-KV partials -> attB bf16 --------------------
__global__ __launch_bounds__(256) void att_combine(const float* __restrict__ opart,
                                                   unsigned short* __restrict__ att) {
    int i = blockIdx.x * 256 + threadIdx.x;       // 786432 threads, 4 d each
    int d4 = i & 15, q = (i >> 4) & 63, qt = (i >> 10) & 31, bh = i >> 15;
    size_t cb = ((size_t)(bh * 32 + qt) * 2) * 4160;
    float4 o0 = *(const float4*)&opart[cb + (size_t)q * 64 + d4 * 4];
    float4 o1 = *(const float4*)&opart[cb + 4160 + (size_t)q * 64 + d4 * 4];
    float rl = 1.0f / (opart[cb + 4096 + q] + opart[cb + 4160 + 4096 + q]);
    int b = bh / 12, h = bh % 12;
    size_t row = (size_t)(b * Ss + qt * 64 + q);
    ushort4 w;
    w.x = f2b((o0.x + o1.x) * rl);
    w.y = f2b((o0.y + o1.y) * rl);
    w.z = f2b((o0.z + o1.z) * rl);
    w.w = f2b((o0.w + o1.w) * rl);
    *(ushort4*)&att[row * Cc + h * HD + d4 * 4] = w;
}

// ---------------- host launch ----------------
extern "C" void kernel_launch(void* const* d_in, const int* in_sizes, int n_in,
                              void* d_out, int out_size, void* d_ws, size_t ws_size,
                              hipStream_t stream) {
    const float* x     = (const float*)d_in[0];
    const float* n1w   = (const float*)d_in[1];
    const float* n1b   = (const float*)d_in[2];
    const float* gamma = (const float*)d_in[3];
    const float* Wf    = (const float*)d_in[4];
    const float* bfu   = (const float*)d_in[5];
    const float* qnw   = (const float*)d_in[6];
    const float* qnb   = (const float*)d_in[7];
    const float* knw   = (const float*)d_in[8];
    const float* knb   = (const float*)d_in[9];
    const float* Wa    = (const float*)d_in[10];
    const float* Wo    = (const float*)d_in[11];
    const float* bo    = (const float*)d_in[12];

    char* ws = (char*)d_ws;
    size_t off = 0;
    auto alloc = [&](size_t bytes) {
        char* p = ws + off;
        off = (off + bytes + 255) & ~(size_t)255;
        return p;
    };
    float*          stat  = (float*)alloc(24 * 2 * 4);
    unsigned short* t     = (unsigned short*)alloc((size_t)BSr * Cc * 2);
    unsigned short* WtF   = (unsigned short*)alloc((size_t)N7 * Cc * 2);
    unsigned short* fused = (unsigned short*)alloc((size_t)BSr * N7 * 2);
    unsigned short* qfB   = (unsigned short*)alloc((size_t)Bb * HE * Ss * HD * 2);
    unsigned short* kfB   = (unsigned short*)alloc((size_t)Bb * HE * Ss * HD * 2);
    unsigned short* vfB   = (unsigned short*)alloc((size_t)Bb * HE * Ss * HD * 2);
    unsigned short* ffa   = (unsigned short*)alloc((size_t)BSr * C2 * 2);
    unsigned short* WtA   = (unsigned short*)alloc((size_t)Cc * Cc * 2);
    unsigned short* WtO   = (unsigned short*)alloc((size_t)Cc * C2 * 2);
    unsigned short* attB  = t;                        // alias (t dead by then)
    float*          oacc  = (float*)fused;            // alias front of fused (dead)
    float*          opart = oacc + (size_t)BSr * Cc;  // alias fused tail (25.6MB fits)

    transpose_w<<<dim3(N7 / 32, Cc / 32), 256, 0, stream>>>(Wf, WtF, Cc, N7);
    transpose_w<<<dim3(Cc / 32, Cc / 32), 256, 0, stream>>>(Wa, WtA, Cc, Cc);
    transpose_w<<<dim3(Cc / 32, C2 / 32), 256, 0, stream>>>(Wo, WtO, C2, Cc);

    gn_stats<<<24, 256, 0, stream>>>(x, stat);
    norm_transpose<<<dim3(Ss / 32, Cc / 32, Bb), 256, 0, stream>>>(x, stat, n1w, n1b, t);

    gemm128<false, true, true><<<dim3(N7 / 128, BSr / 128), 256, 0, stream>>>(
        t, WtF, bfu, fused, BSr, N7, Cc);

    qkv_prep<<<(Bb * Ss * HE) / 4, 256, 0, stream>>>(fused, qnw, qnb, knw, knb, qfB, kfB, vfB);
    ffa_prep<<<(BSr * C2 / 8) / 256, 256, 0, stream>>>(fused, ffa);

    attn64<<<dim3(Ss / 64, Bb * HE, 2), 256, 0, stream>>>(qfB, kfB, vfB, opart);
    att_combine<<<3072, 256, 0, stream>>>(opart, attB);

    gemm128<false, false, false><<<dim3(Cc / 128, BSr / 128), 256, 0, stream>>>(
        attB, WtA, nullptr, oacc, BSr, Cc, Cc);
    gemm_fin<<<dim3(Cc / 128, BSr / 128), 256, 0, stream>>>(
        ffa, WtO, bo, oacc, x, gamma, (float*)d_out, BSr, Cc, C2);
}

// Round 11
// 372.589 us; speedup vs baseline: 1.0201x; 1.0201x over previous
//
#include <hip/hip_runtime.h>
#include <hip/hip_bf16.h>

// ---------------- problem constants ----------------
#define HE   12
#define HD   64
#define Cc   768
#define C2   1536
#define C4   3072
#define N7   5376
#define Bb   2
#define Ss   2048      // H*W*D = 16*16*8
#define BSr  4096      // B*S rows
#define PI_F 3.14159265358979f

using f32x4  = __attribute__((ext_vector_type(4))) float;
using short8 = __attribute__((ext_vector_type(8))) short;

__device__ __forceinline__ unsigned short f2b(float f) {
    union { float f; unsigned int u; } v; v.f = f;
    unsigned int u = v.u;
    unsigned int r = (u + 0x7fffu + ((u >> 16) & 1u)) >> 16;
    return (unsigned short)r;
}
__device__ __forceinline__ unsigned short f2bt(float f) {   // truncating
    union { float f; unsigned int u; } v; v.f = f;
    return (unsigned short)(v.u >> 16);
}
__device__ __forceinline__ float b2f(unsigned short s) {
    union { unsigned int u; float f; } v; v.u = ((unsigned int)s) << 16;
    return v.f;
}
__device__ __forceinline__ f32x4 mfma16(short8 a, short8 b, f32x4 c) {
    return __builtin_amdgcn_mfma_f32_16x16x32_bf16(a, b, c, 0, 0, 0);
}
// async global->LDS, 16 B per lane. LDS dest resolves to wave-uniform base + lane*16.
__device__ __forceinline__ void gl_lds16(const unsigned short* g, unsigned short* l) {
    __builtin_amdgcn_global_load_lds(
        (const __attribute__((address_space(1))) unsigned int*)(const void*)g,
        (__attribute__((address_space(3))) unsigned int*)(void*)l, 16, 0, 0);
}
// bijective XCD swizzle (requires nwg % 8 == 0)
__device__ __forceinline__ void xcd_tile(int& bx, int& by) {
    int nx = gridDim.x;
    int flat = blockIdx.y * nx + blockIdx.x;
    int nwg = nx * gridDim.y;
    int swz = (flat & 7) * (nwg >> 3) + (flat >> 3);
    bx = swz % nx; by = swz / nx;
}

union U8 { uint4 v; unsigned short u[8]; };

// ---------------- 1. tiled transpose f32 -> bf16 (weights) ----------------
__global__ __launch_bounds__(256) void transpose_w(const float* __restrict__ src,
                                                   unsigned short* __restrict__ dst,
                                                   int R, int Ccol) {
    __shared__ float tile[32][33];
    int tx = threadIdx.x & 31, ty = threadIdx.x >> 5;
    int rt = blockIdx.y * 32, ct = blockIdx.x * 32;
#pragma unroll
    for (int i = 0; i < 4; ++i)
        tile[ty + i * 8][tx] = src[(size_t)(rt + ty + i * 8) * Ccol + ct + tx];
    __syncthreads();
#pragma unroll
    for (int i = 0; i < 4; ++i)
        dst[(size_t)(ct + ty + i * 8) * R + rt + tx] = f2b(tile[tx][ty + i * 8]);
}

// ---------------- 2. groupnorm stats ----------------
__global__ __launch_bounds__(256) void gn_stats(const float* __restrict__ x,
                                                float* __restrict__ stat) {
    int j = blockIdx.x;
    const float4* p = (const float4*)(x + (size_t)j * 131072);
    float s = 0.f, ss = 0.f;
    for (int i = threadIdx.x; i < 32768; i += 256) {
        float4 v = p[i];
        s  += v.x + v.y + v.z + v.w;
        ss += v.x * v.x + v.y * v.y + v.z * v.z + v.w * v.w;
    }
#pragma unroll
    for (int m = 1; m < 64; m <<= 1) { s += __shfl_xor(s, m); ss += __shfl_xor(ss, m); }
    __shared__ float ls[4], lss[4];
    int wid = threadIdx.x >> 6;
    if ((threadIdx.x & 63) == 0) { ls[wid] = s; lss[wid] = ss; }
    __syncthreads();
    if (threadIdx.x == 0) {
        s = ls[0] + ls[1] + ls[2] + ls[3];
        ss = lss[0] + lss[1] + lss[2] + lss[3];
        float mu  = s / 131072.0f;
        float var = ss / 131072.0f - mu * mu;
        stat[j * 2]     = mu;
        stat[j * 2 + 1] = rsqrtf(var + 1e-5f);
    }
}

// ---------------- 3. normalize + transpose (B,C,S) -> t bf16 (B*S, C) ----------
__global__ __launch_bounds__(256) void norm_transpose(const float* __restrict__ x,
                                                      const float* __restrict__ stat,
                                                      const float* __restrict__ w,
                                                      const float* __restrict__ bgn,
                                                      unsigned short* __restrict__ t) {
    __shared__ float tile[32][33];
    int b = blockIdx.z;
    int st = blockIdx.x * 32, ct = blockIdx.y * 32;
    int tx = threadIdx.x & 31, ty = threadIdx.x >> 5;
#pragma unroll
    for (int i = 0; i < 4; ++i) {
        int c = ct + ty + i * 8;
        int g = c >> 6;
        float mu = stat[(b * 12 + g) * 2], rs = stat[(b * 12 + g) * 2 + 1];
        float v = x[(size_t)(b * Cc + c) * Ss + st + tx];
        tile[ty + i * 8][tx] = (v - mu) * rs * w[c] + bgn[c];
    }
    __syncthreads();
#pragma unroll
    for (int i = 0; i < 4; ++i) {
        int s = st + ty + i * 8, c = ct + tx;
        t[(size_t)(b * Ss + s) * Cc + c] = f2b(tile[tx][ty + i * 8]);
    }
}

// ---------------- 4. 128x128x32 bf16 GEMM: 2-phase dbuf + deswizzled LDS --------
template<bool ACCUM, bool BIAS, bool OUTBF16>
__global__ __launch_bounds__(256) void gemm128(const unsigned short* __restrict__ A,
                                               const unsigned short* __restrict__ Bt,
                                               const float* __restrict__ bias,
                                               void* __restrict__ Cout,
                                               int M, int N, int K) {
    __shared__ __align__(16) unsigned short As[2][128 * 32];
    __shared__ __align__(16) unsigned short Bs[2][128 * 32];
    const int tid = threadIdx.x;
    const int wid = tid >> 6, lane = tid & 63;
    const int lr = lane & 15, lh = lane >> 4;
    const int wr = wid >> 1, wc = wid & 1;
    int bx, by; xcd_tile(bx, by);
    const int row0 = by * 128, col0 = bx * 128;
    const int srow = tid >> 2;
    const int kcs  = (((tid & 3) ^ ((tid >> 3) & 3)) * 8);
    const unsigned short* ga = A  + (size_t)(row0 + srow) * K + kcs;
    const unsigned short* gb = Bt + (size_t)(col0 + srow) * K + kcs;
    const int csw = ((lr >> 1) & 3) << 3;
    f32x4 acc[4][4] = {};

    auto STAGE = [&](int buf, int k0) {
        gl_lds16(ga + k0,          &As[buf][tid * 8]);
        gl_lds16(ga + 64 * K + k0, &As[buf][2048 + tid * 8]);
        gl_lds16(gb + k0,          &Bs[buf][tid * 8]);
        gl_lds16(gb + 64 * K + k0, &Bs[buf][2048 + tid * 8]);
    };

    STAGE(0, 0);
    __syncthreads();
    for (int k0 = 0; k0 < K; k0 += 32) {
        const int cur = (k0 >> 5) & 1;
        if (k0 + 32 < K) STAGE(cur ^ 1, k0 + 32);
        short8 af[4], bfr[4];
#pragma unroll
        for (int m = 0; m < 4; ++m)
            af[m]  = *(const short8*)&As[cur][(wr * 64 + m * 16 + lr) * 32 + ((lh << 3) ^ csw)];
#pragma unroll
        for (int n = 0; n < 4; ++n)
            bfr[n] = *(const short8*)&Bs[cur][(wc * 64 + n * 16 + lr) * 32 + ((lh << 3) ^ csw)];
#pragma unroll
        for (int m = 0; m < 4; ++m)
#pragma unroll
            for (int n = 0; n < 4; ++n)
                acc[m][n] = mfma16(af[m], bfr[n], acc[m][n]);
        __syncthreads();
    }

#pragma unroll
    for (int m = 0; m < 4; ++m)
#pragma unroll
        for (int n = 0; n < 4; ++n) {
            int row = row0 + wr * 64 + m * 16 + lh * 4;
            int col = col0 + wc * 64 + n * 16 + lr;
            float bv = BIAS ? bias[col] : 0.0f;
#pragma unroll
            for (int r = 0; r < 4; ++r) {
                size_t idx = (size_t)(row + r) * N + col;
                float v = acc[m][n][r] + bv;
                if (ACCUM) v += ((const float*)Cout)[idx];
                if (OUTBF16) ((unsigned short*)Cout)[idx] = f2b(v);
                else         ((float*)Cout)[idx] = v;
            }
        }
}

// ---- 4b. final GEMM: oacc-accumulate + gamma/residual/transpose epilogue ------
__global__ __launch_bounds__(256) void gemm_fin(const unsigned short* __restrict__ A,
                                                const unsigned short* __restrict__ Bt,
                                                const float* __restrict__ bo,
                                                const float* __restrict__ oaccIn,
                                                const float* __restrict__ x,
                                                const float* __restrict__ gamma,
                                                float* __restrict__ out,
                                                int M, int N, int K) {
    __shared__ __align__(16) unsigned short As[2][128 * 32];
    __shared__ __align__(16) unsigned short Bs[2][128 * 32];
    const int tid = threadIdx.x;
    const int wid = tid >> 6, lane = tid & 63;
    const int lr = lane & 15, lh = lane >> 4;
    const int wr = wid >> 1, wc = wid & 1;
    int bx, by; xcd_tile(bx, by);
    const int row0 = by * 128, col0 = bx * 128;
    const int srow = tid >> 2;
    const int kcs  = (((tid & 3) ^ ((tid >> 3) & 3)) * 8);
    const unsigned short* ga = A  + (size_t)(row0 + srow) * K + kcs;
    const unsigned short* gb = Bt + (size_t)(col0 + srow) * K + kcs;
    const int csw = ((lr >> 1) & 3) << 3;
    f32x4 acc[4][4] = {};

    auto STAGE = [&](int buf, int k0) {
        gl_lds16(ga + k0,          &As[buf][tid * 8]);
        gl_lds16(ga + 64 * K + k0, &As[buf][2048 + tid * 8]);
        gl_lds16(gb + k0,          &Bs[buf][tid * 8]);
        gl_lds16(gb + 64 * K + k0, &Bs[buf][2048 + tid * 8]);
    };

    STAGE(0, 0);
    __syncthreads();
    for (int k0 = 0; k0 < K; k0 += 32) {
        const int cur = (k0 >> 5) & 1;
        if (k0 + 32 < K) STAGE(cur ^ 1, k0 + 32);
        short8 af[4], bfr[4];
#pragma unroll
        for (int m = 0; m < 4; ++m)
            af[m]  = *(const short8*)&As[cur][(wr * 64 + m * 16 + lr) * 32 + ((lh << 3) ^ csw)];
#pragma unroll
        for (int n = 0; n < 4; ++n)
            bfr[n] = *(const short8*)&Bs[cur][(wc * 64 + n * 16 + lr) * 32 + ((lh << 3) ^ csw)];
#pragma unroll
        for (int m = 0; m < 4; ++m)
#pragma unroll
            for (int n = 0; n < 4; ++n)
                acc[m][n] = mfma16(af[m], bfr[n], acc[m][n]);
        __syncthreads();
    }

#pragma unroll
    for (int m = 0; m < 4; ++m)
#pragma unroll
        for (int n = 0; n < 4; ++n) {
            int row = row0 + wr * 64 + m * 16 + lh * 4;
            int col = col0 + wc * 64 + n * 16 + lr;
            float bv = bo[col], gv = gamma[col];
#pragma unroll
            for (int r = 0; r < 4; ++r) {
                int rw = row + r;
                float v = acc[m][n][r] + bv + oaccIn[(size_t)rw * N + col];
                int b = rw >> 11, s = rw & 2047;
                size_t oidx = (size_t)(b * Cc + col) * Ss + s;
                out[oidx] = gv * v + x[oidx];
            }
        }
}

// ---------------- 5. per-(b,s,head) LN + RoPE on q,k (V handled separately) -----
__global__ __launch_bounds__(256) void qkv_prep(const unsigned short* __restrict__ fused,
                                                const float* __restrict__ qnw, const float* __restrict__ qnb,
                                                const float* __restrict__ knw, const float* __restrict__ knb,
                                                unsigned short* __restrict__ qf,
                                                unsigned short* __restrict__ kf) {
    const int wid = threadIdx.x >> 6, lane = threadIdx.x & 63;
    const int job = blockIdx.x * 4 + wid;
    const int srow = job / 12, h = job % 12;
    const int b = srow >> 11, s = srow & 2047;

    size_t base = (size_t)srow * N7 + C4 + h * HD;
    float qv = b2f(fused[base + lane]);
    float kv = b2f(fused[base + Cc + lane]);

    float qs = qv, ks = kv;
#pragma unroll
    for (int m = 1; m < 64; m <<= 1) { qs += __shfl_xor(qs, m); ks += __shfl_xor(ks, m); }
    float qmu = qs * (1.0f / 64.0f), kmu = ks * (1.0f / 64.0f);
    float qd = qv - qmu, kd = kv - kmu;
    float qv2 = qd * qd, kv2 = kd * kd;
#pragma unroll
    for (int m = 1; m < 64; m <<= 1) { qv2 += __shfl_xor(qv2, m); kv2 += __shfl_xor(kv2, m); }
    float qn = qd * rsqrtf(qv2 * (1.0f / 64.0f) + 1e-5f) * qnw[lane] + qnb[lane];
    float kn = kd * rsqrtf(kv2 * (1.0f / 64.0f) + 1e-5f) * knw[lane] + knb[lane];

    if (lane < 48) {
        int axis = lane >> 4, ii = (lane & 15) >> 1;
        float basef = (1.0f + (float)ii * (127.0f / 7.0f)) * PI_F;
        int   pos_i = (axis == 0) ? (s >> 7) : (axis == 1) ? ((s >> 3) & 15) : (s & 7);
        float denom = (axis == 2) ? 7.0f : 15.0f;
        float pos   = -1.0f + 2.0f * (float)pos_i / denom;
        float ang   = pos * basef;
        float sn, cs;
        sincosf(ang, &sn, &cs);
        float qp = __shfl_xor(qn, 1);
        float kp = __shfl_xor(kn, 1);
        qn = (lane & 1) ? (qn * cs + qp * sn) : (qn * cs - qp * sn);
        kn = (lane & 1) ? (kn * cs + kp * sn) : (kn * cs - kp * sn);
    }

    size_t obase = ((size_t)(b * 12 + h) * Ss + s) * HD + lane;
    qf[obase] = f2b(qn);
    kf[obase] = f2b(kn);
}

// ---------------- 5b. V^T: vt[bh][d][s] from fused (no norm applied to V) -------
__global__ __launch_bounds__(256) void v_transpose(const unsigned short* __restrict__ fused,
                                                   unsigned short* __restrict__ vt) {
    __shared__ unsigned short tile[64][72];
    const int tid = threadIdx.x;
    const int bh = blockIdx.y, st = blockIdx.x * 64;
    const int b = bh / 12, h = bh % 12;
    const size_t src0 = (size_t)(b * Ss + st) * N7 + C4 + 2 * Cc + h * HD;
#pragma unroll
    for (int j = 0; j < 2; ++j) {
        int e = j * 256 + tid;             // 0..511 : 64 s-rows x 8 col-octets
        int sr = e >> 3, c8 = (e & 7) * 8;
        *(uint4*)&tile[sr][c8] = *(const uint4*)&fused[src0 + (size_t)sr * N7 + c8];
    }
    __syncthreads();
#pragma unroll
    for (int j = 0; j < 2; ++j) {
        int e = j * 256 + tid;
        int d = e >> 3, s8 = (e & 7) * 8;
        U8 o;
#pragma unroll
        for (int jj = 0; jj < 8; ++jj) o.u[jj] = tile[s8 + jj][d];
        *(uint4*)&vt[((size_t)bh * HD + d) * Ss + st + s8] = o.v;
    }
}

// ---------------- 6. ffa = silu(gate) * xh ----------------
__global__ __launch_bounds__(256) void ffa_prep(const unsigned short* __restrict__ fused,
                                                unsigned short* __restrict__ ffa) {
    int i8 = blockIdx.x * 256 + threadIdx.x;
    int row = i8 / 192, co = (i8 % 192) * 8;
    U8 xa, ga, oa;
    xa.v = *(const uint4*)&fused[(size_t)row * N7 + co];
    ga.v = *(const uint4*)&fused[(size_t)row * N7 + C2 + co];
#pragma unroll
    for (int j = 0; j < 8; ++j) {
        float g = b2f(ga.u[j]);
        float xh = b2f(xa.u[j]);
        float sg = 1.0f / (1.0f + __expf(-g));
        oa.u[j] = f2b(g * sg * xh);
    }
    *(uint4*)&ffa[(size_t)row * C2 + co] = oa.v;
}

// ---------------- 7. flash attention: gl_lds staging, dbuf, fixed-max softmax ---
// K tile [key][d] and V^T tile [d][key] both staged via global_load_lds with
// XOR-swizzled SOURCE (block (lane&7)^(lane>>3)); fragment reads XOR the same
// involution -> 2-way banks (free). One barrier per KV-tile; loads of tile t+1
// fly under compute of tile t (drained by the barrier's vmcnt(0)).
__global__ __launch_bounds__(256) void attn64(const unsigned short* __restrict__ qf,
                                              const unsigned short* __restrict__ kf,
                                              const unsigned short* __restrict__ vt,
                                              unsigned short* __restrict__ att) {
    __shared__ __align__(16) unsigned short Ks[2][64 * 64];
    __shared__ __align__(16) unsigned short Vs[2][64 * 64];
    __shared__ __align__(16) unsigned short Ps[4][16][72];   // wave-private
    const int tid = threadIdx.x, wid = tid >> 6, lane = tid & 63;
    const int lr = lane & 15, lh = lane >> 4;
    const int bh = blockIdx.y, qt = blockIdx.x;
    const int b = bh / 12, h = bh % 12;
    const size_t kbase = (size_t)bh * Ss * HD;   // kf [bh][s][d]
    const size_t vbase = (size_t)bh * HD * Ss;   // vt [bh][d][s]

    const int qrow = qt * 64 + wid * 16 + lr;
    short8 qa0 = *(const short8*)&qf[kbase + (size_t)qrow * HD + lh * 8];
    short8 qa1 = *(const short8*)&qf[kbase + (size_t)qrow * HD + 32 + lh * 8];

    // staging: wave wid covers tile rows wid*16 + j*8 + (lane>>3), j=0,1
    // source col-block = (lane&7) ^ (lane>>3)   (tile_row & 7 == lane>>3)
    const int r0  = wid * 16 + (lane >> 3);
    const int sc0 = ((lane & 7) ^ (lane >> 3)) * 8;
    const unsigned short* ksrc = kf + kbase + (size_t)r0 * HD + sc0;  // +kt*64*HD, +8*HD
    const unsigned short* vsrc = vt + vbase + (size_t)r0 * Ss + sc0;  // +kt*64,    +8*Ss
    const int ldst = wid * 1024 + lane * 8;                            // dest elems

    const short8 ones = {0x3F80, 0x3F80, 0x3F80, 0x3F80, 0x3F80, 0x3F80, 0x3F80, 0x3F80};
    const float c1 = 0.125f * 1.44269504f;     // scale * log2(e)
    const float c2 = 23.08312065f;             // 16 * log2(e)
    const int rxb = (lr >> 2) & 3;             // Ps read swizzle (row = lr)
    const int xr  = lr & 7;                    // K/V read swizzle field

    f32x4 oacc[4] = {};
    f32x4 lacc = {};

    auto STAGE = [&](int buf, int kt) {
        gl_lds16(ksrc + (size_t)(kt * 64) * HD,          &Ks[buf][ldst]);
        gl_lds16(ksrc + (size_t)(kt * 64 + 8) * HD,      &Ks[buf][ldst + 512]);
        gl_lds16(vsrc + kt * 64,                         &Vs[buf][ldst]);
        gl_lds16(vsrc + kt * 64 + 8 * Ss,                &Vs[buf][ldst + 512]);
    };

    STAGE(0, 0);
    __syncthreads();

    for (int kt = 0; kt < 32; ++kt) {
        const int cur = kt & 1;
        if (kt < 31) STAGE(cur ^ 1, kt + 1);   // loads fly under this tile's compute

        // scores: 16 q-rows x 64 keys per wave
        f32x4 sc[4];
        __builtin_amdgcn_s_setprio(1);
#pragma unroll
        for (int n = 0; n < 4; ++n) {
            f32x4 z = {0.f, 0.f, 0.f, 0.f};
            short8 k0 = *(const short8*)&Ks[cur][(n * 16 + lr) * 64 + ((lh ^ xr) & 7) * 8];
            short8 k1 = *(const short8*)&Ks[cur][(n * 16 + lr) * 64 + (((lh + 4) ^ xr) & 7) * 8];
            z = mfma16(qa0, k0, z);
            z = mfma16(qa1, k1, z);
            sc[n] = z;
        }
        __builtin_amdgcn_s_setprio(0);

        // fixed-max softmax: p = exp2(s*c1 - c2), no reductions, no rescale
#pragma unroll
        for (int n = 0; n < 4; ++n)
#pragma unroll
            for (int r = 0; r < 4; ++r)
                sc[n][r] = exp2f(sc[n][r] * c1 - c2);

#pragma unroll
        for (int r = 0; r < 4; ++r) {
            int prow = lh * 4 + r;
            int lo = lr & 7, lr3 = lr >> 3;
            Ps[wid][prow][(((0 + lr3) ^ lh) << 3) | lo] = f2bt(sc[0][r]);
            Ps[wid][prow][(((2 + lr3) ^ lh) << 3) | lo] = f2bt(sc[1][r]);
            Ps[wid][prow][(((4 + lr3) ^ lh) << 3) | lo] = f2bt(sc[2][r]);
            Ps[wid][prow][(((6 + lr3) ^ lh) << 3) | lo] = f2bt(sc[3][r]);
        }

        // PV: out(16x64) += P(16x64) @ V(64x64) ; l += P @ ones
        short8 pa0 = *(const short8*)&Ps[wid][lr][((lh ^ rxb) & 7) * 8];
        short8 pa1 = *(const short8*)&Ps[wid][lr][(((lh + 4) ^ rxb) & 7) * 8];
        __builtin_amdgcn_s_setprio(1);
        lacc = mfma16(pa0, ones, lacc);
        lacc = mfma16(pa1, ones, lacc);
#pragma unroll
        for (int n = 0; n < 4; ++n) {
            short8 v0 = *(const short8*)&Vs[cur][(n * 16 + lr) * 64 + ((lh ^ xr) & 7) * 8];
            short8 v1 = *(const short8*)&Vs[cur][(n * 16 + lr) * 64 + (((lh + 4) ^ xr) & 7) * 8];
            oacc[n] = mfma16(pa0, v0, oacc[n]);
            oacc[n] = mfma16(pa1, v1, oacc[n]);
        }
        __builtin_amdgcn_s_setprio(0);
        __syncthreads();   // tile t reads done; tile t+1 staged (vmcnt drained)
    }

    float rinv[4];
#pragma unroll
    for (int r = 0; r < 4; ++r) rinv[r] = 1.0f / lacc[r];
#pragma unroll
    for (int n = 0; n < 4; ++n)
#pragma unroll
        for (int r = 0; r < 4; ++r) {
            int srow_w = qt * 64 + wid * 16 + lh * 4 + r;
            int col = h * HD + n * 16 + lr;
            att[(size_t)(b * Ss + srow_w) * Cc + col] = f2b(oacc[n][r] * rinv[r]);
        }
}

// ---------------- host launch ----------------
extern "C" void kernel_launch(void* const* d_in, const int* in_sizes, int n_in,
                              void* d_out, int out_size, void* d_ws, size_t ws_size,
                              hipStream_t stream) {
    const float* x     = (const float*)d_in[0];
    const float* n1w   = (const float*)d_in[1];
    const float* n1b   = (const float*)d_in[2];
    const float* gamma = (const float*)d_in[3];
    const float* Wf    = (const float*)d_in[4];
    const float* bfu   = (const float*)d_in[5];
    const float* qnw   = (const float*)d_in[6];
    const float* qnb   = (const float*)d_in[7];
    const float* knw   = (const float*)d_in[8];
    const float* knb   = (const float*)d_in[9];
    const float* Wa    = (const float*)d_in[10];
    const float* Wo    = (const float*)d_in[11];
    const float* bo    = (const float*)d_in[12];

    char* ws = (char*)d_ws;
    size_t off = 0;
    auto alloc = [&](size_t bytes) {
        char* p = ws + off;
        off = (off + bytes + 255) & ~(size_t)255;
        return p;
    };
    float*          stat  = (float*)alloc(24 * 2 * 4);
    unsigned short* t     = (unsigned short*)alloc((size_t)BSr * Cc * 2);
    unsigned short* WtF   = (unsigned short*)alloc((size_t)N7 * Cc * 2);
    unsigned short* fused = (unsigned short*)alloc((size_t)BSr * N7 * 2);
    unsigned short* qfB   = (unsigned short*)alloc((size_t)Bb * HE * Ss * HD * 2);
    unsigned short* kfB   = (unsigned short*)alloc((size_t)Bb * HE * Ss * HD * 2);
    unsigned short* vtB   = (unsigned short*)alloc((size_t)Bb * HE * Ss * HD * 2);
    unsigned short* ffa   = (unsigned short*)alloc((size_t)BSr * C2 * 2);
    unsigned short* WtA   = (unsigned short*)alloc((size_t)Cc * Cc * 2);
    unsigned short* WtO   = (unsigned short*)alloc((size_t)Cc * C2 * 2);
    unsigned short* attB  = t;                       // alias (t dead by then)
    float*          oacc  = (float*)fused;           // alias (fused dead by then)

    transpose_w<<<dim3(N7 / 32, Cc / 32), 256, 0, stream>>>(Wf, WtF, Cc, N7);
    transpose_w<<<dim3(Cc / 32, Cc / 32), 256, 0, stream>>>(Wa, WtA, Cc, Cc);
    transpose_w<<<dim3(Cc / 32, C2 / 32), 256, 0, stream>>>(Wo, WtO, C2, Cc);

    gn_stats<<<24, 256, 0, stream>>>(x, stat);
    norm_transpose<<<dim3(Ss / 32, Cc / 32, Bb), 256, 0, stream>>>(x, stat, n1w, n1b, t);

    gemm128<false, true, true><<<dim3(N7 / 128, BSr / 128), 256, 0, stream>>>(
        t, WtF, bfu, fused, BSr, N7, Cc);

    qkv_prep<<<(Bb * Ss * HE) / 4, 256, 0, stream>>>(fused, qnw, qnb, knw, knb, qfB, kfB);
    v_transpose<<<dim3(Ss / 64, Bb * HE), 256, 0, stream>>>(fused, vtB);
    ffa_prep<<<(BSr * C2 / 8) / 256, 256, 0, stream>>>(fused, ffa);

    attn64<<<dim3(Ss / 64, Bb * HE), 256, 0, stream>>>(qfB, kfB, vtB, attB);

    gemm128<false, false, false><<<dim3(Cc / 128, BSr / 128), 256, 0, stream>>>(
        attB, WtA, nullptr, oacc, BSr, Cc, Cc);
    gemm_fin<<<dim3(Cc / 128, BSr / 128), 256, 0, stream>>>(
        ffa, WtO, bo, oacc, x, gamma, (float*)d_out, BSr, Cc, C2);
}